// Round 6
// baseline (1178.277 us; speedup 1.0000x reference)
//
#include <hip/hip_runtime.h>
#include <cstdint>
#include <cstddef>

#define NPOINT 1024
#define NSAMPLE 32
#define BATCH 8
#define NPTS 4096
#define DFEAT 64
#define CIN 67
#define C1 64
#define C2 64
#define C3 128
#define BN_EPS 1e-5f

// ---------------------------------------------------------------------------
// FPS: one block per batch, 512 threads (8 waves, 2/SIMD), 8 pts/thread in
// scalar registers (proven resident at VGPR~40-56). Bit-exact distances;
// first-index tie-break via lane/wave ordering (ballot+ctz). No global store
// in the step loop: centroids are latched in registers (2 per thread) and
// written coalesced at the end.
// ---------------------------------------------------------------------------
__device__ __forceinline__ float wave64_max_bcast(float v) {
    // values must be >= 0 (bound_ctrl zero-fill loses). Result via lane 63.
    int x;
    x = __builtin_amdgcn_update_dpp(0, __float_as_int(v), 0x111, 0xf, 0xf, true);
    v = fmaxf(v, __int_as_float(x));  // row_shr:1
    x = __builtin_amdgcn_update_dpp(0, __float_as_int(v), 0x112, 0xf, 0xf, true);
    v = fmaxf(v, __int_as_float(x));  // row_shr:2
    x = __builtin_amdgcn_update_dpp(0, __float_as_int(v), 0x114, 0xf, 0xf, true);
    v = fmaxf(v, __int_as_float(x));  // row_shr:4
    x = __builtin_amdgcn_update_dpp(0, __float_as_int(v), 0x118, 0xf, 0xf, true);
    v = fmaxf(v, __int_as_float(x));  // row_shr:8
    x = __builtin_amdgcn_update_dpp(0, __float_as_int(v), 0x142, 0xf, 0xf, true);
    v = fmaxf(v, __int_as_float(x));  // row_bcast:15
    x = __builtin_amdgcn_update_dpp(0, __float_as_int(v), 0x143, 0xf, 0xf, true);
    v = fmaxf(v, __int_as_float(x));  // row_bcast:31
    return __int_as_float(__builtin_amdgcn_readlane(__float_as_int(v), 63));
}

__device__ __forceinline__ float row_max8(float v) {
    // max over lanes 0..7 (values replicated with period 8); result via lane 7.
    int x;
    x = __builtin_amdgcn_update_dpp(0, __float_as_int(v), 0x111, 0xf, 0xf, true);
    v = fmaxf(v, __int_as_float(x));  // row_shr:1
    x = __builtin_amdgcn_update_dpp(0, __float_as_int(v), 0x112, 0xf, 0xf, true);
    v = fmaxf(v, __int_as_float(x));  // row_shr:2
    x = __builtin_amdgcn_update_dpp(0, __float_as_int(v), 0x114, 0xf, 0xf, true);
    v = fmaxf(v, __int_as_float(x));  // row_shr:4
    return __int_as_float(__builtin_amdgcn_readlane(__float_as_int(v), 7));
}

__global__ __launch_bounds__(512) void fps_kernel(const float* __restrict__ xyz,
                                                  float* __restrict__ dout) {
    const int b = blockIdx.x;
    const float* xb = xyz + (size_t)b * 3 * NPTS;
    float* ox = dout + (size_t)b * 3 * NPOINT;

    __shared__ float4 swin[2][8];  // {x, y, z, dist} per wave, double-buffered

    const int t = threadIdx.x;
    const int wv = t >> 6, lane = t & 63;
    constexpr int PT = NPTS / 512;  // 8 points/thread, contiguous
    const int base = t * PT;

    float px[PT], py[PT], pz[PT], dist[PT];
    {
        const float4* fx = (const float4*)(xb + base);
        const float4* fy = (const float4*)(xb + NPTS + base);
        const float4* fz = (const float4*)(xb + 2 * NPTS + base);
#pragma unroll
        for (int q = 0; q < PT / 4; ++q) {
            float4 vx = fx[q], vy = fy[q], vz = fz[q];
            px[4 * q] = vx.x; px[4 * q + 1] = vx.y; px[4 * q + 2] = vx.z; px[4 * q + 3] = vx.w;
            py[4 * q] = vy.x; py[4 * q + 1] = vy.y; py[4 * q + 2] = vy.z; py[4 * q + 3] = vy.w;
            pz[4 * q] = vz.x; pz[4 * q + 1] = vz.y; pz[4 * q + 2] = vz.z; pz[4 * q + 3] = vz.w;
        }
#pragma unroll
        for (int u = 0; u < PT; ++u) dist[u] = 1e10f;
    }

    float cx = xb[0], cy = xb[NPTS], cz = xb[2 * NPTS];
    // per-thread latched output centroids: s == t and s == t + 512
    float o0x = 0.f, o0y = 0.f, o0z = 0.f;
    float o1x = 0.f, o1y = 0.f, o1z = 0.f;
    if (t == 0) { o0x = cx; o0y = cy; o0z = cz; }  // s = 0

    for (int s = 1; s < NPOINT; ++s) {
        float bv = 0.0f;
#pragma unroll
        for (int u = 0; u < PT; ++u) {
            float dx = __fsub_rn(px[u], cx);
            float dy = __fsub_rn(py[u], cy);
            float dz = __fsub_rn(pz[u], cz);
            float d = __fadd_rn(__fadd_rn(__fmul_rn(dx, dx), __fmul_rn(dy, dy)),
                                __fmul_rn(dz, dz));
            float nd = fminf(dist[u], d);
            dist[u] = nd;
            bv = fmaxf(bv, nd);
        }
        const float wmax = wave64_max_bcast(bv);

        // first matching lane (ballot order == ascending point index)
        const unsigned long long m = __ballot(bv == wmax);
        const int fl = __builtin_ctzll(m);
        if (lane == fl) {
            // winner-lane rescan: first matching point (descending keeps smallest)
            float ccx = 0.f, ccy = 0.f, ccz = 0.f;
#pragma unroll
            for (int u = PT - 1; u >= 0; --u) {
                if (dist[u] == wmax) { ccx = px[u]; ccy = py[u]; ccz = pz[u]; }
            }
            swin[s & 1][wv] = make_float4(ccx, ccy, ccz, wmax);
        }
        __syncthreads();

        // cross-wave pick: 1 ds_read_b128/thread, 3-step DPP max, ballot+ctz
        const float4 e = swin[s & 1][lane & 7];
        const float gmax = row_max8(e.w);
        const unsigned long long m2 = __ballot(e.w == gmax);
        const int ws = __builtin_ctzll(m2);  // smallest wave id -> smallest idx
        cx = __int_as_float(__builtin_amdgcn_readlane(__float_as_int(e.x), ws));
        cy = __int_as_float(__builtin_amdgcn_readlane(__float_as_int(e.y), ws));
        cz = __int_as_float(__builtin_amdgcn_readlane(__float_as_int(e.z), ws));

        if (s == t) { o0x = cx; o0y = cy; o0z = cz; }
        if (s == t + 512) { o1x = cx; o1y = cy; o1z = cz; }
    }

    // coalesced final writes (1024 centroids, 2 per thread)
    ox[t] = o0x;
    ox[NPOINT + t] = o0y;
    ox[2 * NPOINT + t] = o0z;
    ox[512 + t] = o1x;
    ox[NPOINT + 512 + t] = o1y;
    ox[2 * NPOINT + 512 + t] = o1z;
}

// ---------------------------------------------------------------------------
// Transpose points (B,64,N) -> (B,N,64) so MLP gathers are contiguous.
// ---------------------------------------------------------------------------
__global__ __launch_bounds__(256) void transpose_pts(const float* __restrict__ pts,
                                                     float* __restrict__ ptsT) {
    __shared__ float tile[64][65];
    const int b = blockIdx.x / (NPTS / 64);
    const int n0 = (blockIdx.x % (NPTS / 64)) * 64;
    const int t = threadIdx.x;
    const int nl = t & 63, cq = t >> 6;
    const float* pb = pts + (size_t)b * DFEAT * NPTS;
#pragma unroll
    for (int i = 0; i < 16; ++i) {
        int c = i * 4 + cq;
        tile[c][nl] = pb[(size_t)c * NPTS + n0 + nl];
    }
    __syncthreads();
    float* ob = ptsT + (size_t)b * NPTS * DFEAT;
    const int cl = t & 63, nq = t >> 6;
#pragma unroll
    for (int i = 0; i < 16; ++i) {
        int n = i * 4 + nq;
        ob[(size_t)(n0 + n) * DFEAT + cl] = tile[cl][n];
    }
}

// ---------------------------------------------------------------------------
// Ball query: one wave per query point. First 32 ascending indices with
// d2 <= r2, padded with the first. Bit-exact d2.
// ---------------------------------------------------------------------------
__global__ __launch_bounds__(256) void ballquery_kernel(const float* __restrict__ xyz,
                                                        const float* __restrict__ dout,
                                                        int* __restrict__ idx) {
    const int wv = threadIdx.x >> 6, lane = threadIdx.x & 63;
    const int sg = blockIdx.x * 4 + wv;  // b*NPOINT + s
    const int b = sg / NPOINT, s = sg % NPOINT;
    const float* xb = xyz + (size_t)b * 3 * NPTS;
    const float* nx = dout + (size_t)b * 3 * NPOINT;
    const float cx = nx[s], cy = nx[NPOINT + s], cz = nx[2 * NPOINT + s];
    int* ob = idx + (size_t)sg * NSAMPLE;
    const float r2 = 0.04f;  // f32(0.2*0.2)

    int cnt = 0;
    int first = -1;
    for (int tch = 0; tch < NPTS / 64 && cnt < NSAMPLE; ++tch) {
        const int j = tch * 64 + lane;
        float dx = __fsub_rn(cx, xb[j]);
        float dy = __fsub_rn(cy, xb[NPTS + j]);
        float dz = __fsub_rn(cz, xb[2 * NPTS + j]);
        float d2 = __fadd_rn(__fadd_rn(__fmul_rn(dx, dx), __fmul_rn(dy, dy)),
                             __fmul_rn(dz, dz));
        unsigned long long mask = __ballot(d2 <= r2);
        while (mask && cnt < NSAMPLE) {
            int bit = __builtin_ctzll(mask);
            int pj = tch * 64 + bit;
            if (cnt == 0) first = pj;
            if (lane == 0) ob[cnt] = pj;
            cnt++;
            mask &= mask - 1;
        }
    }
    if (lane == 0) {
        for (int r = cnt; r < NSAMPLE; ++r) ob[r] = first;
    }
}

// ---------------------------------------------------------------------------
// Fused group + 3x conv-BN-ReLU + max over nsample.
// Thread = one (s,k) column; 4-way split accumulators for ILP.
// ---------------------------------------------------------------------------
template <int TRANSPOSED>
__global__ __launch_bounds__(256) void mlp_kernel(
    const float* __restrict__ xyz, const float* __restrict__ pts,
    const int* __restrict__ idx, const float* __restrict__ dnew,
    const float* __restrict__ w0, const float* __restrict__ b0,
    const float* __restrict__ g0, const float* __restrict__ bt0,
    const float* __restrict__ rm0, const float* __restrict__ rv0,
    const float* __restrict__ w1, const float* __restrict__ b1,
    const float* __restrict__ g1, const float* __restrict__ bt1,
    const float* __restrict__ rm1, const float* __restrict__ rv1,
    const float* __restrict__ w2, const float* __restrict__ b2,
    const float* __restrict__ g2, const float* __restrict__ bt2,
    const float* __restrict__ rm2, const float* __restrict__ rv2,
    float* __restrict__ outf) {
    __shared__ float ylds[64][256];
    const int t = threadIdx.x;
    const int k = t & 31, sl = t >> 5;
    const int b = blockIdx.x >> 7;
    const int s = (blockIdx.x & 127) * 8 + sl;
    const int p = idx[((size_t)(b * NPOINT + s)) * NSAMPLE + k];

    const float* xb = xyz + (size_t)b * 3 * NPTS;
    const float* nx = dnew + (size_t)b * 3 * NPOINT;

    float x[CIN];
    x[0] = xb[p] - nx[s];
    x[1] = xb[NPTS + p] - nx[NPOINT + s];
    x[2] = xb[2 * NPTS + p] - nx[2 * NPOINT + s];
    if (TRANSPOSED) {
        const float* pb = pts + ((size_t)b * NPTS + p) * DFEAT;
#pragma unroll
        for (int c = 0; c < DFEAT; ++c) x[3 + c] = pb[c];
    } else {
        const float* pb = pts + (size_t)b * DFEAT * NPTS + p;
#pragma unroll
        for (int c = 0; c < DFEAT; ++c) x[3 + c] = pb[(size_t)c * NPTS];
    }

    // layer 1: 67 -> 64
    for (int o = 0; o < C1; ++o) {
        const float* wr = w0 + o * CIN;
        float a0 = 0.f, a1 = 0.f, a2 = 0.f, a3 = 0.f;
#pragma unroll
        for (int c = 0; c < 64; c += 4) {
            a0 = fmaf(wr[c], x[c], a0);
            a1 = fmaf(wr[c + 1], x[c + 1], a1);
            a2 = fmaf(wr[c + 2], x[c + 2], a2);
            a3 = fmaf(wr[c + 3], x[c + 3], a3);
        }
        a0 = fmaf(wr[64], x[64], a0);
        a1 = fmaf(wr[65], x[65], a1);
        a2 = fmaf(wr[66], x[66], a2);
        float acc = (a0 + a1) + (a2 + a3);
        float sc = g0[o] * rsqrtf(rv0[o] + BN_EPS);
        float y = fmaf(sc, acc + b0[o] - rm0[o], bt0[o]);
        ylds[o][t] = fmaxf(y, 0.f);
    }
    __syncthreads();
    float x1[C1];
#pragma unroll
    for (int c = 0; c < C1; ++c) x1[c] = ylds[c][t];
    __syncthreads();

    // layer 2: 64 -> 64
    for (int o = 0; o < C2; ++o) {
        const float* wr = w1 + o * C1;
        float a0 = 0.f, a1 = 0.f, a2 = 0.f, a3 = 0.f;
#pragma unroll
        for (int c = 0; c < C1; c += 4) {
            a0 = fmaf(wr[c], x1[c], a0);
            a1 = fmaf(wr[c + 1], x1[c + 1], a1);
            a2 = fmaf(wr[c + 2], x1[c + 2], a2);
            a3 = fmaf(wr[c + 3], x1[c + 3], a3);
        }
        float acc = (a0 + a1) + (a2 + a3);
        float sc = g1[o] * rsqrtf(rv1[o] + BN_EPS);
        float y = fmaf(sc, acc + b1[o] - rm1[o], bt1[o]);
        ylds[o][t] = fmaxf(y, 0.f);
    }
    __syncthreads();
    float x2[C2];
#pragma unroll
    for (int c = 0; c < C2; ++c) x2[c] = ylds[c][t];

    // layer 3: 64 -> 128, then max over k (32 lanes sharing s)
    float* ob = outf + (size_t)b * C3 * NPOINT;
    for (int o = 0; o < C3; ++o) {
        const float* wr = w2 + o * C2;
        float a0 = 0.f, a1 = 0.f, a2 = 0.f, a3 = 0.f;
#pragma unroll
        for (int c = 0; c < C2; c += 4) {
            a0 = fmaf(wr[c], x2[c], a0);
            a1 = fmaf(wr[c + 1], x2[c + 1], a1);
            a2 = fmaf(wr[c + 2], x2[c + 2], a2);
            a3 = fmaf(wr[c + 3], x2[c + 3], a3);
        }
        float acc = (a0 + a1) + (a2 + a3);
        float sc = g2[o] * rsqrtf(rv2[o] + BN_EPS);
        float y = fmaf(sc, acc + b2[o] - rm2[o], bt2[o]);
        float v = fmaxf(y, 0.f);
#pragma unroll
        for (int m = 16; m >= 1; m >>= 1) v = fmaxf(v, __shfl_xor(v, m, 32));
        if (k == 0) ob[(size_t)o * NPOINT + s] = v;
    }
}

// ---------------------------------------------------------------------------
extern "C" void kernel_launch(void* const* d_in, const int* in_sizes, int n_in,
                              void* d_out, int out_size, void* d_ws, size_t ws_size,
                              hipStream_t stream) {
    const float* xyz = (const float*)d_in[0];
    const float* pts = (const float*)d_in[1];
    const float* w0 = (const float*)d_in[2];
    const float* b0 = (const float*)d_in[3];
    const float* g0 = (const float*)d_in[4];
    const float* bt0 = (const float*)d_in[5];
    const float* rm0 = (const float*)d_in[6];
    const float* rv0 = (const float*)d_in[7];
    const float* w1 = (const float*)d_in[8];
    const float* b1 = (const float*)d_in[9];
    const float* g1 = (const float*)d_in[10];
    const float* bt1 = (const float*)d_in[11];
    const float* rm1 = (const float*)d_in[12];
    const float* rv1 = (const float*)d_in[13];
    const float* w2 = (const float*)d_in[14];
    const float* b2 = (const float*)d_in[15];
    const float* g2 = (const float*)d_in[16];
    const float* bt2 = (const float*)d_in[17];
    const float* rm2 = (const float*)d_in[18];
    const float* rv2 = (const float*)d_in[19];

    float* out = (float*)d_out;
    float* outf = out + (size_t)BATCH * 3 * NPOINT;

    const size_t idx_bytes = (size_t)BATCH * NPOINT * NSAMPLE * sizeof(int);  // 1 MB
    const size_t idx_pad = (idx_bytes + 255) & ~(size_t)255;
    const size_t ptsT_bytes = (size_t)BATCH * NPTS * DFEAT * sizeof(float);   // 8 MB
    int* idx = (int*)d_ws;
    float* ptsT = (float*)((char*)d_ws + idx_pad);
    const bool useT = ws_size >= idx_pad + ptsT_bytes;

    fps_kernel<<<BATCH, 512, 0, stream>>>(xyz, out);
    if (useT) transpose_pts<<<BATCH * (NPTS / 64), 256, 0, stream>>>(pts, ptsT);
    ballquery_kernel<<<BATCH * NPOINT / 4, 256, 0, stream>>>(xyz, out, idx);
    if (useT) {
        mlp_kernel<1><<<BATCH * NPOINT / 8, 256, 0, stream>>>(
            xyz, ptsT, idx, out, w0, b0, g0, bt0, rm0, rv0, w1, b1, g1, bt1, rm1,
            rv1, w2, b2, g2, bt2, rm2, rv2, outf);
    } else {
        mlp_kernel<0><<<BATCH * NPOINT / 8, 256, 0, stream>>>(
            xyz, pts, idx, out, w0, b0, g0, bt0, rm0, rv0, w1, b1, g1, bt1, rm1,
            rv1, w2, b2, g2, bt2, rm2, rv2, outf);
    }
}